// Round 7
// baseline (54.603 us; speedup 1.0000x reference)
//
#include <hip/hip_runtime.h>

// MultiHeadDense: out[b] = x[b] @ W[idx[b]] + bias[idx[b]]
// B=4096, D=1024, F=1024, H=8. fp32 in/out; bf16 MFMA internally.
// Round 7: the gload_lds barrier-step structure caps at ~26GB/s/CU staged.
// -> NO LDS staging in the GEMM. Ap/Wt are pre-packed in MFMA FRAGMENT
//    ORDER so each lane's bf16x8 fragment is one global_load_dwordx4 to
//    registers, streamed from L2 (head<->XCD affinity). 64x64 wave tiles,
//    4 waves/block K-split (256 each), LDS only for the final reduction.
//    1024 working blocks x 4 waves = 16 waves/CU, zero mid-loop barriers.
//
// Fragment layout (both A and B panels): [grp16][kc][kg][r][8 bf16]
//   grp16 = row/16, kc = k/32, kg = (k/8)%4, r = row%16, e = k%8
//   lane l of a frag load reads chunk (kg=l>>4, r=l&15) -> addr = base + l*16B.

typedef __attribute__((ext_vector_type(8))) short bf16x8;
typedef __attribute__((ext_vector_type(4))) float f32x4;

static __device__ __forceinline__ unsigned short f2bf(float f) {
  union { float f; unsigned int u; } c; c.f = f;
  unsigned int u = c.u;
  return (unsigned short)((u + 0x7fffu + ((u >> 16) & 1u)) >> 16);
}

// Kernel 1 (fused): blocks 0..2047 transpose+convert W [H][D][F] fp32 ->
// Wt fragment-packed (rows = F, k = D). Block 2048: counting-sort scan of
// idx -> rows[] + cnt[] + base16[] (16-aligned head bases; gaps zero-filled).
__global__ __launch_bounds__(256) void k_prep(
    const float* __restrict__ W, const int* __restrict__ idx,
    unsigned short* __restrict__ Wt, int* __restrict__ cnt,
    int* __restrict__ base16, int* __restrict__ rows) {
  const int bid = blockIdx.x;
  const int t = threadIdx.x;

  if (bid >= 2048) {
    __shared__ int sc[256][8];
    int myi[16];
#pragma unroll
    for (int i = 0; i < 4; ++i) {
      const int4 v = *(const int4*)(idx + t * 16 + i * 4);
      myi[i * 4 + 0] = v.x; myi[i * 4 + 1] = v.y;
      myi[i * 4 + 2] = v.z; myi[i * 4 + 3] = v.w;
    }
    int c[8];
#pragma unroll
    for (int h = 0; h < 8; ++h) c[h] = 0;
#pragma unroll
    for (int e = 0; e < 16; ++e)
#pragma unroll
      for (int h = 0; h < 8; ++h) c[h] += (myi[e] == h) ? 1 : 0;

    int val[8];
#pragma unroll
    for (int h = 0; h < 8; ++h) { val[h] = c[h]; sc[t][h] = c[h]; }
    __syncthreads();
    for (int off = 1; off < 256; off <<= 1) {
      int nb[8];
#pragma unroll
      for (int h = 0; h < 8; ++h) nb[h] = (t >= off) ? sc[t - off][h] : 0;
      __syncthreads();
#pragma unroll
      for (int h = 0; h < 8; ++h) { val[h] += nb[h]; sc[t][h] = val[h]; }
      __syncthreads();
    }
    int tot[8], excl[8];
#pragma unroll
    for (int h = 0; h < 8; ++h) tot[h] = sc[255][h];
#pragma unroll
    for (int h = 0; h < 8; ++h) excl[h] = val[h] - c[h];
    int bases[9];
    bases[0] = 0;
#pragma unroll
    for (int h = 0; h < 7; ++h) bases[h + 1] = (bases[h] + tot[h] + 15) & ~15;
    bases[8] = bases[7] + tot[7];
#pragma unroll
    for (int h = 0; h < 8; ++h) {
      int pos = bases[h] + excl[h];
#pragma unroll
      for (int e = 0; e < 16; ++e) {
        if (myi[e] == h) { rows[pos] = t * 16 + e; ++pos; }
      }
    }
    // zero-fill head-alignment gaps (<=15 each) and tail up to 4352
    if (t < 128) {
      const int hh = t >> 4, j = t & 15;
      const int pos = bases[hh] + tot[hh] + j;
      if (pos < bases[hh + 1]) rows[pos] = 0;
    }
    {
      const int pos = bases[8] + t;
      if (pos < 4352) rows[pos] = 0;
    }
    if (t < 8) cnt[t] = tot[t];
    if (t == 0) {
#pragma unroll
      for (int h = 0; h < 9; ++h) base16[h] = bases[h];
    }
    return;
  }

  // ---- transpose block: 64x64 tile of head h (d = k, f = out-row) ----
  __shared__ unsigned short tile[64][65];
  const int h = bid >> 8;
  const int rem = bid & 255;
  const int d0 = (rem >> 4) << 6;
  const int f0 = (rem & 15) << 6;
  {
    const int c4 = (t & 15) * 4;
    const int r0 = t >> 4;
#pragma unroll
    for (int i = 0; i < 4; ++i) {
      const int r = r0 + i * 16;
      const float4 v = *(const float4*)(W + (size_t)(h * 1024 + d0 + r) * 1024 + f0 + c4);
      tile[r][c4 + 0] = f2bf(v.x);
      tile[r][c4 + 1] = f2bf(v.y);
      tile[r][c4 + 2] = f2bf(v.z);
      tile[r][c4 + 3] = f2bf(v.w);
    }
  }
  __syncthreads();
  // store fragment-packed: thread t -> fgl = t>>6, fr = t&15, ksl = (t>>4)&3
  const int fgl = t >> 6;
  const int fr = t & 15;
  const int ksl = (t >> 4) & 3;
  const int frow = f0 + fgl * 16 + fr;
  const int fg = frow >> 4;
  const int kc = (d0 >> 5) + (ksl >> 1);
  const int kg0 = (ksl & 1) * 2;
  const size_t baseB = (((size_t)(h * 64 + fg) * 32) + kc) * 1024;  // bytes
#pragma unroll
  for (int q = 0; q < 4; ++q) {
    const int kg = kg0 + (q >> 1);
    const int e = (q & 1) * 4;
    const int dl = ksl * 16 + (q >> 1) * 8 + e;  // d-local of first elem
    ushort4 o;
    o.x = tile[dl + 0][fgl * 16 + fr];
    o.y = tile[dl + 1][fgl * 16 + fr];
    o.z = tile[dl + 2][fgl * 16 + fr];
    o.w = tile[dl + 3][fgl * 16 + fr];
    *(ushort4*)((char*)Wt + baseB + kg * 256 + fr * 16 + e * 2) = o;
  }
}

// Kernel 2: gather X rows -> Ap fragment-packed. Block = (group of 16
// slots, k-half). LDS roundtrip so both global sides are coalesced.
__global__ __launch_bounds__(256) void k_gather(
    const float* __restrict__ X, const int* __restrict__ rows,
    unsigned short* __restrict__ Ap) {
  __shared__ unsigned short lb[16][520];  // 16 rows x 512 bf16 (+8 pad)
  const int g = blockIdx.x >> 1;
  const int kh = blockIdx.x & 1;
  const int t = threadIdx.x;
  // load: r = t>>4 reads its X row's k-half, 16B per iter
  {
    const int r = t >> 4, cp = t & 15;
    const int b = rows[g * 16 + r];
    const float* xr = X + (size_t)b * 1024 + kh * 512;
#pragma unroll
    for (int i = 0; i < 8; ++i) {
      const int k4 = (i * 16 + cp) * 4;
      const float4 v = *(const float4*)(xr + k4);
      ushort4 o;
      o.x = f2bf(v.x); o.y = f2bf(v.y); o.z = f2bf(v.z); o.w = f2bf(v.w);
      *(ushort4*)(&lb[r][k4]) = o;
    }
  }
  __syncthreads();
  // store: chunk c (16B) = kh*1024 + t + 256*i, decode (kc,kg,r)
#pragma unroll
  for (int i = 0; i < 4; ++i) {
    const int cl = t + 256 * i;            // chunk within half
    const int c = kh * 1024 + cl;
    const int rr = c & 15;
    const int kg = (c >> 4) & 3;
    const int kcl = cl >> 6;               // k-chunk local to half
    const bf16x8 v = *(const bf16x8*)(&lb[rr][kcl * 32 + kg * 8]);
    *(bf16x8*)((char*)Ap + (size_t)g * 32768 + (size_t)c * 16) = v;
  }
}

// Kernel 3: grouped GEMM, register-direct fragments (no LDS tiles, no
// mid-loop barriers). Block = (h, mt64, nt64); 4 waves split K (256 each,
// 8 steps of K=32); cross-wave reduce via 36KB LDS; wave 0 scatters out.
__global__ __launch_bounds__(256, 4) void k_gemm(
    const unsigned short* __restrict__ Ap, const unsigned short* __restrict__ Wt,
    const int* __restrict__ rows, const int* __restrict__ cnt,
    const int* __restrict__ base16,
    const float* __restrict__ bias, float* __restrict__ out) {
  __shared__ float red[2][64 * 72];  // row stride 72 -> 2-way-free banks

  const int blk = blockIdx.x;
  const int h = blk & 7;           // head -> XCD affinity
  const int nt = (blk >> 3) & 15;  // 16 n-tiles of 64
  const int mt = blk >> 7;         // up to 64 m-tiles of 64

  const int cnt_h = cnt[h];
  const int basep = base16[h];
  const int m0 = mt * 64;
  if (m0 >= cnt_h) return;
  const int n0 = nt * 64;

  const int t = threadIdx.x;
  const int lane = t & 63;
  const int w = t >> 6;            // K-quarter owner

  const int mb16 = (basep + m0) >> 4;
  const int nb16 = h * 64 + (n0 >> 4);
  const char* Abase = (const char*)Ap + (size_t)mb16 * 32768 + (size_t)(w * 8) * 1024 + lane * 16;
  const char* Bbase = (const char*)Wt + (size_t)nb16 * 32768 + (size_t)(w * 8) * 1024 + lane * 16;

  f32x4 acc[4][4];
#pragma unroll
  for (int m = 0; m < 4; ++m)
#pragma unroll
    for (int n = 0; n < 4; ++n)
      acc[m][n] = (f32x4){0.f, 0.f, 0.f, 0.f};

#pragma unroll
  for (int s = 0; s < 8; ++s) {
    bf16x8 af[4], bfr[4];
#pragma unroll
    for (int mg = 0; mg < 4; ++mg)
      af[mg] = *(const bf16x8*)(Abase + (size_t)mg * 32768 + s * 1024);
#pragma unroll
    for (int ng = 0; ng < 4; ++ng)
      bfr[ng] = *(const bf16x8*)(Bbase + (size_t)ng * 32768 + s * 1024);
#pragma unroll
    for (int mg = 0; mg < 4; ++mg)
#pragma unroll
      for (int ng = 0; ng < 4; ++ng)
        acc[mg][ng] = __builtin_amdgcn_mfma_f32_16x16x32_bf16(af[mg], bfr[ng], acc[mg][ng], 0, 0, 0);
  }

  // cross-wave K reduction through LDS
  const int rl = (lane >> 4) * 4;      // row-sub base
  const int cl = lane & 15;            // col within 16
  if (w >= 2) {
#pragma unroll
    for (int mg = 0; mg < 4; ++mg)
#pragma unroll
      for (int j = 0; j < 4; ++j)
#pragma unroll
        for (int ng = 0; ng < 4; ++ng)
          red[w - 2][(mg * 16 + rl + j) * 72 + ng * 16 + cl] = acc[mg][ng][j];
  }
  __syncthreads();
  if (w < 2) {
#pragma unroll
    for (int mg = 0; mg < 4; ++mg)
#pragma unroll
      for (int j = 0; j < 4; ++j)
#pragma unroll
        for (int ng = 0; ng < 4; ++ng)
          acc[mg][ng][j] += red[w][(mg * 16 + rl + j) * 72 + ng * 16 + cl];
  }
  __syncthreads();
  if (w == 1) {
#pragma unroll
    for (int mg = 0; mg < 4; ++mg)
#pragma unroll
      for (int j = 0; j < 4; ++j)
#pragma unroll
        for (int ng = 0; ng < 4; ++ng)
          red[0][(mg * 16 + rl + j) * 72 + ng * 16 + cl] = acc[mg][ng][j];
  }
  __syncthreads();
  if (w == 0) {
    float bv[4];
#pragma unroll
    for (int ng = 0; ng < 4; ++ng)
      bv[ng] = bias[h * 1024 + n0 + ng * 16 + cl];
#pragma unroll
    for (int mg = 0; mg < 4; ++mg) {
#pragma unroll
      for (int j = 0; j < 4; ++j) {
        const int lr = mg * 16 + rl + j;
        if (m0 + lr < cnt_h) {
          const int b = rows[basep + m0 + lr];
#pragma unroll
          for (int ng = 0; ng < 4; ++ng) {
            const float v = acc[mg][ng][j] + red[0][lr * 72 + ng * 16 + cl] + bv[ng];
            out[(size_t)b * 1024 + n0 + ng * 16 + cl] = v;
          }
        }
      }
    }
  }
}

extern "C" void kernel_launch(void* const* d_in, const int* in_sizes, int n_in,
                              void* d_out, int out_size, void* d_ws, size_t ws_size,
                              hipStream_t stream) {
  const float* X = (const float*)d_in[0];
  const int* idx = (const int*)d_in[1];
  const float* W = (const float*)d_in[2];
  const float* bias = (const float*)d_in[3];
  float* out = (float*)d_out;

  char* ws = (char*)d_ws;
  int* cnt = (int*)ws;                                   // 8 ints @ 0
  int* base16 = (int*)(ws + 64);                         // 9 ints @ 64
  int* rows = (int*)(ws + 256);                          // 4352 ints
  unsigned short* Wt = (unsigned short*)(ws + 32768);    // 512 grp16 x 32KB = 16 MB
  unsigned short* Ap = (unsigned short*)(ws + 32768 + 16777216);  // 272 grp16 x 32KB

  k_prep<<<dim3(2049), 256, 0, stream>>>(W, idx, Wt, cnt, base16, rows);
  k_gather<<<dim3(544), 256, 0, stream>>>(X, rows, Ap);
  // 8 heads (xcd-affine) x 16 n-tiles x 64 m-tiles (early-return past cnt_h)
  k_gemm<<<dim3(8 * 16 * 64), 256, 0, stream>>>(Ap, Wt, rows, cnt, base16, bias, out);
}